// Round 1
// baseline (1066.878 us; speedup 1.0000x reference)
//
#include <hip/hip_runtime.h>

#define BB 32
#define NN 512
#define FF 128
#define K4 2048
#define ALPHA 0.2f
#define THRESH 0.6f
#define NEGINF -9e15f

__device__ __forceinline__ float lrelu(float x) { return x > 0.f ? x : ALPHA * x; }

// u1[f] = sum_g W[g,f]*a[g];  u2[f] = sum_g W[g,f]*a[F+g]
__global__ void k_u(const float* __restrict__ W, const float* __restrict__ a,
                    float* __restrict__ u12) {
    int f = threadIdx.x;  // 0..127
    float s1 = 0.f, s2 = 0.f;
    for (int g = 0; g < FF; ++g) {
        float w = W[g * FF + f];
        s1 += w * a[g];
        s2 += w * a[FF + g];
    }
    u12[f] = s1;
    u12[FF + f] = s2;
}

// Wh1[row] = h[row,:]·u1 ; Wh2[row] = h[row,:]·u2   (row = b*N+n)
__global__ void k_wh12(const float* __restrict__ h, const float* __restrict__ u12,
                       float* __restrict__ Wh12) {
    int row = blockIdx.x;
    int f = threadIdx.x;  // 128 threads
    float hv = h[(long)row * FF + f];
    float p1 = hv * u12[f], p2 = hv * u12[FF + f];
#pragma unroll
    for (int o = 1; o < 64; o <<= 1) {
        p1 += __shfl_xor(p1, o, 64);
        p2 += __shfl_xor(p2, o, 64);
    }
    __shared__ float s1[2], s2[2];
    int w = f >> 6;
    if ((f & 63) == 0) { s1[w] = p1; s2[w] = p2; }
    __syncthreads();
    if (f == 0) {
        Wh12[row] = s1[0] + s1[1];
        Wh12[BB * NN + row] = s2[0] + s2[1];
    }
}

// e[b,i,j] = leaky(Wh1[b,i] + Wh2[b,j])
__global__ void k_e(const float* __restrict__ Wh12, float* __restrict__ E) {
    int i = blockIdx.x, b = blockIdx.y, t = threadIdx.x;  // 128 threads
    float w1 = Wh12[b * NN + i];
    const float* w2 = Wh12 + BB * NN + b * NN;
    int j = t * 4;
    float4 v = *(const float4*)(w2 + j);
    float4 o;
    o.x = lrelu(w1 + v.x);
    o.y = lrelu(w1 + v.y);
    o.z = lrelu(w1 + v.z);
    o.w = lrelu(w1 + v.w);
    *(float4*)(E + ((long)b * NN + i) * NN + j) = o;
}

// Generic TN GEMM: C[m,n] = epi( sum_k A[m,k]*B[n,k] )
// A row-major lda=K, B row-major ldb=K, C row-major ldc=Nc.
// MODE 0: plain store. MODE 1: sigmoid. MODE 2: adj-mask (reads E, writes in place).
template <int MODE>
__global__ __launch_bounds__(256) void k_gemm_tn(
    const float* __restrict__ A, const float* __restrict__ Bm, float* __restrict__ C,
    int M, int Nc, int K, long sA, long sC, const float* __restrict__ E, long sE) {
    int bz = blockIdx.z;
    const float* Ab = A + (long)bz * sA;
    float* Cb = C + (long)bz * sC;
    int bm = blockIdx.y * 64, bn = blockIdx.x * 64;
    __shared__ float As[32][68];
    __shared__ float Bs[32][68];
    int tid = threadIdx.x;
    int tx = tid & 15, ty = tid >> 4;
    float acc[4][4] = {{0.f}};
    int r = tid >> 3, q = tid & 7;
    const float* Ap = Ab + (long)(bm + r) * K + q * 4;
    const float* Bp = Bm + (long)(bn + r) * K + q * 4;
    for (int k0 = 0; k0 < K; k0 += 32) {
        float4 a0 = *(const float4*)(Ap + k0);
        float4 a1 = *(const float4*)(Ap + k0 + 32 * (long)K);
        float4 b0 = *(const float4*)(Bp + k0);
        float4 b1 = *(const float4*)(Bp + k0 + 32 * (long)K);
        __syncthreads();
        As[q * 4 + 0][r] = a0.x; As[q * 4 + 1][r] = a0.y;
        As[q * 4 + 2][r] = a0.z; As[q * 4 + 3][r] = a0.w;
        As[q * 4 + 0][r + 32] = a1.x; As[q * 4 + 1][r + 32] = a1.y;
        As[q * 4 + 2][r + 32] = a1.z; As[q * 4 + 3][r + 32] = a1.w;
        Bs[q * 4 + 0][r] = b0.x; Bs[q * 4 + 1][r] = b0.y;
        Bs[q * 4 + 2][r] = b0.z; Bs[q * 4 + 3][r] = b0.w;
        Bs[q * 4 + 0][r + 32] = b1.x; Bs[q * 4 + 1][r + 32] = b1.y;
        Bs[q * 4 + 2][r + 32] = b1.z; Bs[q * 4 + 3][r + 32] = b1.w;
        __syncthreads();
#pragma unroll
        for (int kk = 0; kk < 32; ++kk) {
            float av[4], bv[4];
            *(float4*)av = *(const float4*)&As[kk][ty * 4];
            *(float4*)bv = *(const float4*)&Bs[kk][tx * 4];
#pragma unroll
            for (int i = 0; i < 4; ++i)
#pragma unroll
                for (int j = 0; j < 4; ++j) acc[i][j] = fmaf(av[i], bv[j], acc[i][j]);
        }
    }
#pragma unroll
    for (int i = 0; i < 4; ++i) {
        int m = bm + ty * 4 + i;
#pragma unroll
        for (int j = 0; j < 4; ++j) {
            int n = bn + tx * 4 + j;
            float v = acc[i][j];
            long idx = (long)m * Nc + n;
            if (MODE == 0) {
                Cb[idx] = v;
            } else if (MODE == 1) {
                Cb[idx] = 1.f / (1.f + expf(-v));
            } else {
                float e = E[(long)bz * sE + idx];
                float adj = e + v;
                Cb[idx] = (adj > THRESH) ? e : NEGINF;
            }
        }
    }
}

// Row softmax in place over L[b*N+n, 0..511]
__global__ __launch_bounds__(256) void k_softmax(float* __restrict__ L) {
    long row = blockIdx.x;
    float* p = L + row * NN;
    int t = threadIdx.x;
    float v0 = p[t], v1 = p[t + 256];
    float m = fmaxf(v0, v1);
#pragma unroll
    for (int o = 1; o < 64; o <<= 1) m = fmaxf(m, __shfl_xor(m, o, 64));
    __shared__ float red[4], red2[4];
    int w = t >> 6;
    if ((t & 63) == 0) red[w] = m;
    __syncthreads();
    m = fmaxf(fmaxf(red[0], red[1]), fmaxf(red[2], red[3]));
    float e0 = expf(v0 - m), e1 = expf(v1 - m);
    float s = e0 + e1;
#pragma unroll
    for (int o = 1; o < 64; o <<= 1) s += __shfl_xor(s, o, 64);
    if ((t & 63) == 0) red2[w] = s;
    __syncthreads();
    s = red2[0] + red2[1] + red2[2] + red2[3];
    float inv = 1.f / s;
    p[t] = e0 * inv;
    p[t + 256] = e1 * inv;
}

// out[b,m,f] = elu( sum_k Att[b,m,k] * Wh[b,k,f] )
__global__ __launch_bounds__(256) void k_av(const float* __restrict__ Att,
                                            const float* __restrict__ Wh,
                                            float* __restrict__ out) {
    int bz = blockIdx.z;
    int bm = blockIdx.y * 64;
    const float* Ab = Att + (long)bz * NN * NN;
    const float* Bb = Wh + (long)bz * NN * FF;
    __shared__ float As[32][68];
    __shared__ float Bs[32][132];
    int tid = threadIdx.x;
    int tx = tid & 15, ty = tid >> 4;
    float acc[4][8] = {{0.f}};
    int r = tid >> 3, q = tid & 7;
    int fq = tid & 31, rr = tid >> 5;
    for (int k0 = 0; k0 < NN; k0 += 32) {
        float4 a0 = *(const float4*)(Ab + (long)(bm + r) * NN + k0 + q * 4);
        float4 a1 = *(const float4*)(Ab + (long)(bm + r + 32) * NN + k0 + q * 4);
        float4 b0 = *(const float4*)(Bb + (long)(k0 + rr) * FF + fq * 4);
        float4 b1 = *(const float4*)(Bb + (long)(k0 + rr + 8) * FF + fq * 4);
        float4 b2 = *(const float4*)(Bb + (long)(k0 + rr + 16) * FF + fq * 4);
        float4 b3 = *(const float4*)(Bb + (long)(k0 + rr + 24) * FF + fq * 4);
        __syncthreads();
        As[q * 4 + 0][r] = a0.x; As[q * 4 + 1][r] = a0.y;
        As[q * 4 + 2][r] = a0.z; As[q * 4 + 3][r] = a0.w;
        As[q * 4 + 0][r + 32] = a1.x; As[q * 4 + 1][r + 32] = a1.y;
        As[q * 4 + 2][r + 32] = a1.z; As[q * 4 + 3][r + 32] = a1.w;
        *(float4*)&Bs[rr][fq * 4] = b0;
        *(float4*)&Bs[rr + 8][fq * 4] = b1;
        *(float4*)&Bs[rr + 16][fq * 4] = b2;
        *(float4*)&Bs[rr + 24][fq * 4] = b3;
        __syncthreads();
#pragma unroll
        for (int kk = 0; kk < 32; ++kk) {
            float av[4], bv[8];
            *(float4*)av = *(const float4*)&As[kk][ty * 4];
            *(float4*)&bv[0] = *(const float4*)&Bs[kk][tx * 8];
            *(float4*)&bv[4] = *(const float4*)&Bs[kk][tx * 8 + 4];
#pragma unroll
            for (int i = 0; i < 4; ++i)
#pragma unroll
                for (int j = 0; j < 8; ++j) acc[i][j] = fmaf(av[i], bv[j], acc[i][j]);
        }
    }
#pragma unroll
    for (int i = 0; i < 4; ++i) {
        int m = bm + ty * 4 + i;
#pragma unroll
        for (int j = 0; j < 8; ++j) {
            int f = tx * 8 + j;
            float v = acc[i][j];
            out[(long)bz * NN * FF + (long)m * FF + f] = v > 0.f ? v : expm1f(v);
        }
    }
}

extern "C" void kernel_launch(void* const* d_in, const int* in_sizes, int n_in,
                              void* d_out, int out_size, void* d_ws, size_t ws_size,
                              hipStream_t stream) {
    const float* h = (const float*)d_in[0];
    const float* W = (const float*)d_in[1];
    const float* a = (const float*)d_in[2];
    const float* A0 = (const float*)d_in[3];
    const float* A2 = (const float*)d_in[4];
    float* out = (float*)d_out;

    char* ws = (char*)d_ws;
    size_t ofs = 0;
    auto alloc = [&](size_t bytes) -> float* {
        float* p = (float*)(ws + ofs);
        ofs = (ofs + bytes + 255) & ~(size_t)255;
        return p;
    };
    float* u12 = alloc(2 * FF * sizeof(float));
    float* Wh12 = alloc(2 * (size_t)BB * NN * sizeof(float));
    float* Wh = alloc((size_t)BB * NN * FF * sizeof(float));
    float* E = alloc((size_t)BB * NN * NN * sizeof(float));
    size_t sbytes = (size_t)NN * K4 * sizeof(float);  // 4 MB per batch
    size_t avail = ws_size > ofs ? ws_size - ofs : 0;
    int CB = (int)(avail / sbytes);
    if (CB > BB) CB = BB;
    if (CB < 1) CB = 1;
    float* S = (float*)(ws + ofs);

    k_u<<<1, 128, 0, stream>>>(W, a, u12);
    // Wh = h @ W^T as one 16384x128x128 TN GEMM
    k_gemm_tn<0><<<dim3(FF / 64, (BB * NN) / 64, 1), 256, 0, stream>>>(
        h, W, Wh, BB * NN, FF, FF, 0, 0, nullptr, 0);
    k_wh12<<<BB * NN, 128, 0, stream>>>(h, u12, Wh12);
    k_e<<<dim3(NN, BB), 128, 0, stream>>>(Wh12, E);

    for (int c0 = 0; c0 < BB; c0 += CB) {
        int cb = (BB - c0) < CB ? (BB - c0) : CB;
        // S = sigmoid(E @ A0^T)   [512 x 2048] per batch
        k_gemm_tn<1><<<dim3(K4 / 64, NN / 64, cb), 256, 0, stream>>>(
            E + (long)c0 * NN * NN, A0, S, NN, K4, NN, (long)NN * NN, (long)NN * K4,
            nullptr, 0);
        // outer = S @ A2^T; adj = e + outer; L = adj>0.6 ? e : -9e15 (in place over E)
        k_gemm_tn<2><<<dim3(NN / 64, NN / 64, cb), 256, 0, stream>>>(
            S, A2, E + (long)c0 * NN * NN, NN, NN, K4, (long)NN * K4, (long)NN * NN,
            E + (long)c0 * NN * NN, (long)NN * NN);
    }

    k_softmax<<<BB * NN, 256, 0, stream>>>(E);
    k_av<<<dim3(1, NN / 64, BB), 256, 0, stream>>>(E, Wh, out);
}